// Round 6
// baseline (221.310 us; speedup 1.0000x reference)
//
#include <hip/hip_runtime.h>

// FraudDetectionModel: out = Linear(2,1)( chain_{l=0..31} [ tanh(h@W_l^T+b_l)*scale_l+shift_l ] (x) )
// B = 8388608 independent rows of a 2-dim recurrence.
//
// g-substitution: track g = 1/(exp2(c*z)+1), c = 2*log2(e); tanh = 1-2g folds into
// the next affine: M_{l+1} = -2c W_{l+1} diag(s_l), C_{l+1} = c(b_{l+1}+W_{l+1}(s_l+t_l)).
// Calibrated issue model (R3+R5 busy fits): cost = 2*nVALU + 11.5*nTRANS cyc per wave.
//
// Round-6: 8-way batched reciprocal. 4 rows (8 dims) share ONE v_rcp via a
// product/inverse tree (21 mul + 1 rcp per 8 dims, depth 3+3):
//   per 4 rows: 45 V + 9 T = 198 cyc  (was 18 V + 6 T per 2 rows = 216 cyc/4rows), -8.3%.
// Overflow: P = prod(exp2(zs_i)+1) needs sum of positive zs > 128 to overflow
// (~15 sigma for this data distribution, P ~ 1e-50) -> safe. P >= 1 so no underflow.

constexpr int LAYERS = 32;
constexpr int BLOCK  = 256;
constexpr int R4     = 8;   // float4 x-loads per thread = 16 rows/thread = 4 batches of 4 rows

__device__ __forceinline__ float fast_exp2(float x) {
#if __has_builtin(__builtin_amdgcn_exp2f)
    return __builtin_amdgcn_exp2f(x);
#else
    return exp2f(x);
#endif
}
__device__ __forceinline__ float fast_rcp(float x) {
#if __has_builtin(__builtin_amdgcn_rcpf)
    return __builtin_amdgcn_rcpf(x);
#else
    return 1.0f / x;
#endif
}

// 8 sigmoid-denominators -> 8 g = 1/(exp2(zs)+1) with a single v_rcp.
// Product tree up (7 mul), rcp at root, inverse tree down (6 mul), leaves (8 mul).
__device__ __forceinline__ void batch_g8(const float zs[8], float g[8]) {
    float d0 = fast_exp2(zs[0]) + 1.0f;
    float d1 = fast_exp2(zs[1]) + 1.0f;
    float d2 = fast_exp2(zs[2]) + 1.0f;
    float d3 = fast_exp2(zs[3]) + 1.0f;
    float d4 = fast_exp2(zs[4]) + 1.0f;
    float d5 = fast_exp2(zs[5]) + 1.0f;
    float d6 = fast_exp2(zs[6]) + 1.0f;
    float d7 = fast_exp2(zs[7]) + 1.0f;
    float p01 = d0*d1, p23 = d2*d3, p45 = d4*d5, p67 = d6*d7;
    float q0  = p01*p23, q1 = p45*p67;
    float R   = fast_rcp(q0*q1);
    float rA  = R*q1;            // 1/q0
    float rB  = R*q0;            // 1/q1
    float r01 = rA*p23;          // 1/p01
    float r23 = rA*p01;          // 1/p23
    float r45 = rB*p67;          // 1/p45
    float r67 = rB*p45;          // 1/p67
    g[0] = r01*d1; g[1] = r01*d0;
    g[2] = r23*d3; g[3] = r23*d2;
    g[4] = r45*d5; g[5] = r45*d4;
    g[6] = r67*d7; g[7] = r67*d6;
}

__global__ __launch_bounds__(BLOCK, 8) void fraud_fwd(
        const float* __restrict__ x,      // [B,2]
        const float* __restrict__ W,      // [32,2,2]
        const float* __restrict__ b,      // [32,2]
        const float* __restrict__ scale,  // [32,2]
        const float* __restrict__ shift,  // [32,2]
        const float* __restrict__ w_out,  // [1,2]
        const float* __restrict__ b_out,  // [1]
        float* __restrict__ out)          // [B,1]
{
    __shared__ float sP[LAYERS * 8];  // per layer: m00,m01,m10,m11,C0,C1,pad,pad (32B stride)
    __shared__ float sF[4];           // Mo0, Mo1, Co, pad

    const int t = threadIdx.x;
    const float c = 2.885390081777927f;  // 2*log2(e)

    if (t < LAYERS) {
        float w00 = W[t*4+0], w01 = W[t*4+1], w10 = W[t*4+2], w11 = W[t*4+3];
        float b0 = b[t*2+0], b1 = b[t*2+1];
        float m00, m01, m10, m11, C0, C1;
        if (t > 0) {
            float s0 = scale[(t-1)*2+0], s1 = scale[(t-1)*2+1];
            float u0 = s0 + shift[(t-1)*2+0], u1 = s1 + shift[(t-1)*2+1];
            C0 = c * (b0 + w00*u0 + w01*u1);
            C1 = c * (b1 + w10*u0 + w11*u1);
            float k = -2.0f * c;
            m00 = k*w00*s0; m01 = k*w01*s1;
            m10 = k*w10*s0; m11 = k*w11*s1;
        } else {
            C0 = c*b0; C1 = c*b1;
            m00 = c*w00; m01 = c*w01; m10 = c*w10; m11 = c*w11;
        }
        sP[t*8+0] = m00; sP[t*8+1] = m01;
        sP[t*8+2] = m10; sP[t*8+3] = m11;
        sP[t*8+4] = C0;  sP[t*8+5] = C1;
        sP[t*8+6] = 0.f; sP[t*8+7] = 0.f;
    } else if (t == LAYERS) {
        float s0 = scale[31*2+0], s1 = scale[31*2+1];
        float u0 = s0 + shift[31*2+0], u1 = s1 + shift[31*2+1];
        float wo0 = w_out[0], wo1 = w_out[1];
        sF[0] = -2.0f * wo0 * s0;
        sF[1] = -2.0f * wo1 * s1;
        sF[2] = b_out[0] + wo0*u0 + wo1*u1;
        sF[3] = 0.f;
    }
    __syncthreads();

    const float4* __restrict__ xv = (const float4*)x;   // one float4 = 2 rows
    float2*       __restrict__ ov = (float2*)out;       // one float2 = 2 rows' outputs
    const int base4 = blockIdx.x * (BLOCK * R4) + t;    // block-interleaved -> coalesced

    float gx[2*R4], gy[2*R4];

    // Layer 0: from raw x. Batch 4 rows (2 float4) per tree.
    {
        const float4 m0 = *(const float4*)&sP[0];
        const float C0 = sP[4], C1 = sP[5];
        #pragma unroll
        for (int bi = 0; bi < R4/2; ++bi) {        // 4 batches of 4 rows
            float4 a0 = xv[base4 + (2*bi+0)*BLOCK];
            float4 a1 = xv[base4 + (2*bi+1)*BLOCK];
            float zs[8], g[8];
            zs[0] = fmaf(a0.x, m0.x, fmaf(a0.y, m0.y, C0));
            zs[1] = fmaf(a0.x, m0.z, fmaf(a0.y, m0.w, C1));
            zs[2] = fmaf(a0.z, m0.x, fmaf(a0.w, m0.y, C0));
            zs[3] = fmaf(a0.z, m0.z, fmaf(a0.w, m0.w, C1));
            zs[4] = fmaf(a1.x, m0.x, fmaf(a1.y, m0.y, C0));
            zs[5] = fmaf(a1.x, m0.z, fmaf(a1.y, m0.w, C1));
            zs[6] = fmaf(a1.z, m0.x, fmaf(a1.w, m0.y, C0));
            zs[7] = fmaf(a1.z, m0.z, fmaf(a1.w, m0.w, C1));
            batch_g8(zs, g);
            #pragma unroll
            for (int r = 0; r < 4; ++r) {
                gx[4*bi + r] = g[2*r+0];
                gy[4*bi + r] = g[2*r+1];
            }
        }
    }

    // Layers 1..31: 4 batches of 4 rows per layer, one rcp per batch.
    #pragma unroll 4
    for (int l = 1; l < LAYERS; ++l) {
        const float4 m  = *(const float4*)&sP[l*8];
        const float C0 = sP[l*8+4];
        const float C1 = sP[l*8+5];
        #pragma unroll
        for (int bi = 0; bi < 4; ++bi) {
            float zs[8], g[8];
            #pragma unroll
            for (int r = 0; r < 4; ++r) {
                float ga = gx[4*bi + r], gb = gy[4*bi + r];
                zs[2*r+0] = fmaf(ga, m.x, fmaf(gb, m.y, C0));
                zs[2*r+1] = fmaf(ga, m.z, fmaf(gb, m.w, C1));
            }
            batch_g8(zs, g);
            #pragma unroll
            for (int r = 0; r < 4; ++r) {
                gx[4*bi + r] = g[2*r+0];
                gy[4*bi + r] = g[2*r+1];
            }
        }
    }

    // Output fold: out = Co + Mo0*gx + Mo1*gy
    const float Mo0 = sF[0], Mo1 = sF[1], Co = sF[2];
    #pragma unroll
    for (int i = 0; i < R4; ++i) {
        float2 o;
        o.x = fmaf(gx[2*i+0], Mo0, fmaf(gy[2*i+0], Mo1, Co));
        o.y = fmaf(gx[2*i+1], Mo0, fmaf(gy[2*i+1], Mo1, Co));
        ov[base4 + i*BLOCK] = o;
    }
}

extern "C" void kernel_launch(void* const* d_in, const int* in_sizes, int n_in,
                              void* d_out, int out_size, void* d_ws, size_t ws_size,
                              hipStream_t stream) {
    const float* x     = (const float*)d_in[0];
    const float* W     = (const float*)d_in[1];
    const float* b     = (const float*)d_in[2];
    const float* scale = (const float*)d_in[3];
    const float* shift = (const float*)d_in[4];
    const float* w_out = (const float*)d_in[5];
    const float* b_out = (const float*)d_in[6];
    float* out = (float*)d_out;

    const int B = in_sizes[0] / 2;               // 8388608
    const int rows_per_block = BLOCK * R4 * 2;   // 4096
    const int blocks = B / rows_per_block;       // 2048 = 8 blocks/CU, one uniform round

    fraud_fwd<<<blocks, BLOCK, 0, stream>>>(x, W, b, scale, shift, w_out, b_out, out);
}